// Round 9
// baseline (772.138 us; speedup 1.0000x reference)
//
#include <hip/hip_runtime.h>
#include <math.h>

#define BB 16384
#define DD 4096
#define EE 64
#define TK 8
#define RT 32            // rows per block; grid = 512
#define KQ 1024          // K-quarter per wave (R8: was K-half 2048)
#define NCH 16           // chunks of 64 per K-quarter

typedef __attribute__((ext_vector_type(8))) short s16x8;
typedef __attribute__((ext_vector_type(4))) float f32x4;

__device__ inline unsigned pack_hi2(float a, float b) {
    return (__float_as_uint(a) >> 16) | (__float_as_uint(b) & 0xFFFF0000u);
}
__device__ inline float hi_part(float a) {
    return __uint_as_float(__float_as_uint(a) & 0xFFFF0000u);
}
__device__ inline void split_pack(const float4& v0, const float4& v1, uint4& h, uint4& l) {
    h.x = pack_hi2(v0.x, v0.y); h.y = pack_hi2(v0.z, v0.w);
    h.z = pack_hi2(v1.x, v1.y); h.w = pack_hi2(v1.z, v1.w);
    l.x = pack_hi2(v0.x - hi_part(v0.x), v0.y - hi_part(v0.y));
    l.y = pack_hi2(v0.z - hi_part(v0.z), v0.w - hi_part(v0.w));
    l.z = pack_hi2(v1.x - hi_part(v1.x), v1.y - hi_part(v1.y));
    l.w = pack_hi2(v1.z - hi_part(v1.z), v1.w - hi_part(v1.w));
}

// ---------------------------------------------------------------------------
// prep: [wg | wn] fp32 -> bf16 hi/lo in MFMA B-fragment order (verified r2-5).
// ws layout: [kchunk(64)][sub(2)][prec(2)][ntile(8)][lane(64)][16B]
// ---------------------------------------------------------------------------
__global__ __launch_bounds__(256, 1)
void prep_w(const float* __restrict__ wg, const float* __restrict__ wn,
            char* __restrict__ wsB)
{
    __shared__ float Wtmp[64 * 132];
    const int t  = threadIdx.x;
    const int kc = blockIdx.x;

#pragma unroll
    for (int i = 0; i < 8; ++i) {
        int fid = t + i * 256;
        int m   = fid >> 10;
        int id  = fid & 1023;
        int kk  = id >> 4;
        int n4  = id & 15;
        const float* src = (m ? wn : wg) + (size_t)(kc * 64 + kk) * EE + n4 * 4;
        float4 v = *(const float4*)src;
        *(float4*)&Wtmp[kk * 132 + m * 64 + n4 * 4] = v;
    }
    __syncthreads();

#pragma unroll
    for (int i = 0; i < 4; ++i) {
        int id  = t + i * 256;
        int sub = id >> 9;
        int nt  = (id >> 6) & 7;
        int ln  = id & 63;
        int n   = nt * 16 + (ln & 15);
        int k0  = sub * 32 + (ln >> 4) * 8;
        float f[8];
#pragma unroll
        for (int j = 0; j < 8; ++j) f[j] = Wtmp[(k0 + j) * 132 + n];
        uint4 h, l;
        h.x = pack_hi2(f[0], f[1]); h.y = pack_hi2(f[2], f[3]);
        h.z = pack_hi2(f[4], f[5]); h.w = pack_hi2(f[6], f[7]);
        l.x = pack_hi2(f[0] - hi_part(f[0]), f[1] - hi_part(f[1]));
        l.y = pack_hi2(f[2] - hi_part(f[2]), f[3] - hi_part(f[3]));
        l.z = pack_hi2(f[4] - hi_part(f[4]), f[5] - hi_part(f[5]));
        l.w = pack_hi2(f[6] - hi_part(f[6]), f[7] - hi_part(f[7]));
        size_t base = (size_t)kc * 32768;
        *(uint4*)(wsB + base + (size_t)(((sub * 2 + 0) * 8 + nt) * 64 + ln) * 16) = h;
        *(uint4*)(wsB + base + (size_t)(((sub * 2 + 1) * 8 + nt) * 64 + ln) * 16) = l;
    }
}

// ---------------------------------------------------------------------------
// main: 512 blocks x 512 threads (R8: was 256). Block = 32 rows x 128 cols.
// 8 waves = (nh 0..1) x (ks 0..3): wave tile 32m x 64n over K-quarter 1024.
// R8 rationale (rocprof r4): Occupancy 21% (2 waves/SIMD, grid-limited),
// MfmaUtil 10%, VALU 20%, HBM 10.6% -> latency-bound, nothing to overlap
// stalls with. Doubling waves/block at halved per-wave K doubles waves/SIMD
// to 4 while keeping the verified inner body byte-identical. VGPR must stay
// <=128 for 4 waves/EU: launch_bounds(512,4); body measured 100 VGPR at r4.
// No LDS/barriers in K-loop; sched_barrier(0) pins batched load issue
// (r5 failure: compiler sank loads -> serial latency chain).
// ---------------------------------------------------------------------------
__global__ __launch_bounds__(512, 4)
void moe_mfma(const float* __restrict__ x,
              const float* __restrict__ noise,
              const char* __restrict__ wsB,
              float* __restrict__ gates,
              float* __restrict__ dst,      // partials (atomicTail=0) or load (=1)
              int atomicTail)
{
    __shared__ float Ls[RT * 132];   // 16896 B combined-logits tile
    __shared__ float red[512];

    const int tid  = threadIdx.x;
    const int w    = tid >> 6;       // 0..7
    const int lane = tid & 63;
    const int nh   = w & 1;          // n-half: cols nh*64 .. +63
    const int ks   = w >> 1;         // K-quarter: k in [ks*1024, ks*1024+1024)
    const int rb   = blockIdx.x * RT;

    const int m16 = lane & 15;
    const int q   = lane >> 4;

    const float* xr0 = x + (size_t)(rb + m16) * DD + ks * KQ + q * 8;
    const float* xr1 = xr0 + (size_t)16 * DD;
    const uint4* bbase = (const uint4*)wsB + (size_t)ks * NCH * 2048 + nh * 4 * 64 + lane;

    f32x4 acc[2][4];
#pragma unroll
    for (int mt = 0; mt < 2; ++mt)
#pragma unroll
        for (int nt = 0; nt < 4; ++nt) acc[mt][nt] = (f32x4){0.f, 0.f, 0.f, 0.f};

    auto load_A = [&](int ch, float4* a) {
#pragma unroll
        for (int mt = 0; mt < 2; ++mt)
#pragma unroll
            for (int sub = 0; sub < 2; ++sub) {
                const float* p = (mt ? xr1 : xr0) + ch * 64 + sub * 32;
                a[(mt * 2 + sub) * 2 + 0] = *(const float4*)p;
                a[(mt * 2 + sub) * 2 + 1] = *(const float4*)(p + 4);
            }
    };
    auto load_B = [&](int ch, int sub, uint4* b) {
        const uint4* p = bbase + (size_t)ch * 2048;
#pragma unroll
        for (int prec = 0; prec < 2; ++prec)
#pragma unroll
            for (int nt = 0; nt < 4; ++nt)
                b[prec * 4 + nt] = p[((sub * 2 + prec) * 8 + nt) * 64];
    };
    auto compute_sub = [&](const float4* a, int sub, const uint4* b) {
#pragma unroll
        for (int mt = 0; mt < 2; ++mt) {
            uint4 h, l;
            split_pack(a[(mt * 2 + sub) * 2 + 0], a[(mt * 2 + sub) * 2 + 1], h, l);
            const s16x8 ah = __builtin_bit_cast(s16x8, h);
            const s16x8 al = __builtin_bit_cast(s16x8, l);
#pragma unroll
            for (int nt = 0; nt < 4; ++nt) {
                const s16x8 bh = __builtin_bit_cast(s16x8, b[nt]);
                const s16x8 bl = __builtin_bit_cast(s16x8, b[4 + nt]);
                acc[mt][nt] = __builtin_amdgcn_mfma_f32_16x16x32_bf16(ah, bh, acc[mt][nt], 0, 0, 0);
                acc[mt][nt] = __builtin_amdgcn_mfma_f32_16x16x32_bf16(ah, bl, acc[mt][nt], 0, 0, 0);
                acc[mt][nt] = __builtin_amdgcn_mfma_f32_16x16x32_bf16(al, bh, acc[mt][nt], 0, 0, 0);
            }
        }
    };

    float4 A0[8], A1[8];
    uint4  B0[8], B1[8];
    load_A(0, A0);
    load_B(0, 0, B0);
    load_B(0, 1, B1);
    __builtin_amdgcn_sched_barrier(0);

    for (int ch = 0; ch < NCH; ch += 2) {
        // ---- chunk ch : consumes A0, B0(sub0), B1(sub1) ----
        load_A(ch + 1, A1);                       // HBM prefetch, 1 chunk ahead
        __builtin_amdgcn_sched_barrier(0);        // pin: issue before compute
        compute_sub(A0, 0, B0);
        load_B(ch + 1, 0, B0);                    // L2 refill, 1 chunk ahead
        __builtin_amdgcn_sched_barrier(0);
        compute_sub(A0, 1, B1);
        load_B(ch + 1, 1, B1);
        __builtin_amdgcn_sched_barrier(0);

        // ---- chunk ch+1 : consumes A1, refreshed B0/B1 ----
        const int nx = (ch + 2 < NCH) ? ch + 2 : NCH - 1;  // clamped redundant prefetch
        load_A(nx, A0);
        __builtin_amdgcn_sched_barrier(0);
        compute_sub(A1, 0, B0);
        load_B(nx, 0, B0);
        __builtin_amdgcn_sched_barrier(0);
        compute_sub(A1, 1, B1);
        load_B(nx, 1, B1);
        __builtin_amdgcn_sched_barrier(0);
    }

    // ---- combine K-quarters in LDS (the only barriers in the kernel) ----
    const int q4 = lane >> 4, cc = lane & 15;
    if (ks == 0) {
#pragma unroll
        for (int mt = 0; mt < 2; ++mt)
#pragma unroll
            for (int nt = 0; nt < 4; ++nt)
#pragma unroll
                for (int r = 0; r < 4; ++r)
                    Ls[(mt * 16 + q4 * 4 + r) * 132 + nh * 64 + nt * 16 + cc] = acc[mt][nt][r];
    }
    __syncthreads();
    if (ks == 1) {
#pragma unroll
        for (int mt = 0; mt < 2; ++mt)
#pragma unroll
            for (int nt = 0; nt < 4; ++nt)
#pragma unroll
                for (int r = 0; r < 4; ++r)
                    Ls[(mt * 16 + q4 * 4 + r) * 132 + nh * 64 + nt * 16 + cc] += acc[mt][nt][r];
    }
    __syncthreads();
    if (ks == 2) {
#pragma unroll
        for (int mt = 0; mt < 2; ++mt)
#pragma unroll
            for (int nt = 0; nt < 4; ++nt)
#pragma unroll
                for (int r = 0; r < 4; ++r)
                    Ls[(mt * 16 + q4 * 4 + r) * 132 + nh * 64 + nt * 16 + cc] += acc[mt][nt][r];
    }
    __syncthreads();
    if (ks == 3) {
#pragma unroll
        for (int mt = 0; mt < 2; ++mt)
#pragma unroll
            for (int nt = 0; nt < 4; ++nt)
#pragma unroll
                for (int r = 0; r < 4; ++r)
                    Ls[(mt * 16 + q4 * 4 + r) * 132 + nh * 64 + nt * 16 + cc] += acc[mt][nt][r];
    }
    __syncthreads();

    // ---- fused epilogue (verified r1-5): wave-per-row, lane = expert ----
    // R8: 8 waves x 4 rows each.
    float loadAcc = 0.f;
    for (int rr = 0; rr < 4; ++rr) {
        const int row = w * 4 + rr;
        const float clean = Ls[row * 132 + lane];
        const float rawn  = Ls[row * 132 + 64 + lane];
        const float nz    = noise[(size_t)(rb + row) * EE + lane];

        const float sp = fmaxf(rawn, 0.f) + log1pf(expf(-fabsf(rawn)));
        const float sd = sp + 0.01f;
        const float noisy = clean + nz * sd;

        float m = noisy;
#pragma unroll
        for (int off = 32; off; off >>= 1) m = fmaxf(m, __shfl_xor(m, off));
        const float ex = expf(noisy - m);
        float s = ex;
#pragma unroll
        for (int off = 32; off; off >>= 1) s += __shfl_xor(s, off);
        const float p = ex / s;

        float cur = p;
        int selrank = -1;
        float v[9];
#pragma unroll
        for (int j = 0; j < 9; ++j) {
            float bv = cur;
            int   bi = lane;
#pragma unroll
            for (int off = 32; off; off >>= 1) {
                const float ov = __shfl_xor(bv, off);
                const int   oi = __shfl_xor(bi, off);
                if (ov > bv || (ov == bv && oi < bi)) { bv = ov; bi = oi; }
            }
            v[j] = bv;
            if (lane == bi) { cur = -1.f; if (j < TK) selrank = j; }
        }

        float denom = 0.f;
#pragma unroll
        for (int j = 0; j < TK; ++j) denom += expf(v[j] - v[0]);
        const float gate = (selrank >= 0) ? (expf(p - v[0]) / denom) : 0.f;
        gates[(size_t)(rb + row) * EE + lane] = gate;

        const float thr_in  = v[8];
        const float thr_out = v[7];
        const bool  is_in   = noisy > thr_in;
        const float a = (clean - (is_in ? thr_in : thr_out)) / sd;
        loadAcc += 0.5f * (1.f + erff(a * 0.70710678118654752f));
    }

    red[w * 64 + lane] = loadAcc;
    __syncthreads();
    if (tid < 64) {
        float s = 0.f;
#pragma unroll
        for (int i = 0; i < 8; ++i) s += red[i * 64 + tid];
        if (atomicTail) atomicAdd(&dst[tid], s);                 // fallback path
        else            dst[(size_t)blockIdx.x * 64 + tid] = s;  // coalesced
    }
}

// ---------------------------------------------------------------------------
// reduce: 512x64 partials -> load[64]. One block; coalesced column reads.
// ---------------------------------------------------------------------------
__global__ __launch_bounds__(256, 1)
void reduce_load(const float* __restrict__ partial, float* __restrict__ load)
{
    __shared__ float red2[256];
    const int t   = threadIdx.x;
    const int e   = t & 63;
    const int seg = t >> 6;          // 4 segments x 128 blocks
    float s = 0.f;
#pragma unroll 4
    for (int b = seg * 128; b < seg * 128 + 128; ++b)
        s += partial[(size_t)b * 64 + e];
    red2[t] = s;
    __syncthreads();
    if (t < 64)
        load[t] = red2[t] + red2[64 + t] + red2[128 + t] + red2[192 + t];
}

extern "C" void kernel_launch(void* const* d_in, const int* in_sizes, int n_in,
                              void* d_out, int out_size, void* d_ws, size_t ws_size,
                              hipStream_t stream)
{
    const float* x     = (const float*)d_in[0];
    const float* wg    = (const float*)d_in[1];
    const float* wn    = (const float*)d_in[2];
    const float* noise = (const float*)d_in[3];
    float* gates = (float*)d_out;
    float* load  = (float*)d_out + (size_t)BB * EE;
    char*  wsB   = (char*)d_ws;                          // 2 MB B-stream

    const size_t wsB_bytes     = (size_t)(DD / 64) * 32768;          // 2 MB
    const size_t partial_bytes = (size_t)(BB / RT) * EE * sizeof(float); // 128 KB
    const bool   fits = ws_size >= wsB_bytes + partial_bytes;

    hipLaunchKernelGGL(prep_w, dim3(DD / 64), dim3(256), 0, stream, wg, wn, wsB);

    if (fits) {
        float* partial = (float*)(wsB + wsB_bytes);
        hipLaunchKernelGGL(moe_mfma, dim3(BB / RT), dim3(512), 0, stream,
                           x, noise, wsB, gates, partial, 0);
        hipLaunchKernelGGL(reduce_load, dim3(1), dim3(256), 0, stream, partial, load);
    } else {
        // harness-verified fallback: memset + device-scope atomic tail
        hipMemsetAsync(load, 0, EE * sizeof(float), stream);
        hipLaunchKernelGGL(moe_mfma, dim3(BB / RT), dim3(512), 0, stream,
                           x, noise, wsB, gates, load, 1);
    }
}

// Round 11
// 501.710 us; speedup vs baseline: 1.5390x; 1.5390x over previous
//
#include <hip/hip_runtime.h>
#include <math.h>

#define BB 16384
#define DD 4096
#define EE 64
#define TK 8
#define RT 16            // rows per block (R10: was 32); grid = 1024
#define NCH 32           // chunks of 64 per K-half (as r4)

typedef __attribute__((ext_vector_type(8))) short s16x8;
typedef __attribute__((ext_vector_type(4))) float f32x4;

__device__ inline unsigned pack_hi2(float a, float b) {
    return (__float_as_uint(a) >> 16) | (__float_as_uint(b) & 0xFFFF0000u);
}
__device__ inline float hi_part(float a) {
    return __uint_as_float(__float_as_uint(a) & 0xFFFF0000u);
}
__device__ inline void split_pack(const float4& v0, const float4& v1, uint4& h, uint4& l) {
    h.x = pack_hi2(v0.x, v0.y); h.y = pack_hi2(v0.z, v0.w);
    h.z = pack_hi2(v1.x, v1.y); h.w = pack_hi2(v1.z, v1.w);
    l.x = pack_hi2(v0.x - hi_part(v0.x), v0.y - hi_part(v0.y));
    l.y = pack_hi2(v0.z - hi_part(v0.z), v0.w - hi_part(v0.w));
    l.z = pack_hi2(v1.x - hi_part(v1.x), v1.y - hi_part(v1.y));
    l.w = pack_hi2(v1.z - hi_part(v1.z), v1.w - hi_part(v1.w));
}

// ---------------------------------------------------------------------------
// prep: [wg | wn] fp32 -> bf16 hi/lo in MFMA B-fragment order (verified r2-5).
// ws layout: [kchunk(64)][sub(2)][prec(2)][ntile(8)][lane(64)][16B]
// ---------------------------------------------------------------------------
__global__ __launch_bounds__(256, 1)
void prep_w(const float* __restrict__ wg, const float* __restrict__ wn,
            char* __restrict__ wsB)
{
    __shared__ float Wtmp[64 * 132];
    const int t  = threadIdx.x;
    const int kc = blockIdx.x;

#pragma unroll
    for (int i = 0; i < 8; ++i) {
        int fid = t + i * 256;
        int m   = fid >> 10;
        int id  = fid & 1023;
        int kk  = id >> 4;
        int n4  = id & 15;
        const float* src = (m ? wn : wg) + (size_t)(kc * 64 + kk) * EE + n4 * 4;
        float4 v = *(const float4*)src;
        *(float4*)&Wtmp[kk * 132 + m * 64 + n4 * 4] = v;
    }
    __syncthreads();

#pragma unroll
    for (int i = 0; i < 4; ++i) {
        int id  = t + i * 256;
        int sub = id >> 9;
        int nt  = (id >> 6) & 7;
        int ln  = id & 63;
        int n   = nt * 16 + (ln & 15);
        int k0  = sub * 32 + (ln >> 4) * 8;
        float f[8];
#pragma unroll
        for (int j = 0; j < 8; ++j) f[j] = Wtmp[(k0 + j) * 132 + n];
        uint4 h, l;
        h.x = pack_hi2(f[0], f[1]); h.y = pack_hi2(f[2], f[3]);
        h.z = pack_hi2(f[4], f[5]); h.w = pack_hi2(f[6], f[7]);
        l.x = pack_hi2(f[0] - hi_part(f[0]), f[1] - hi_part(f[1]));
        l.y = pack_hi2(f[2] - hi_part(f[2]), f[3] - hi_part(f[3]));
        l.z = pack_hi2(f[4] - hi_part(f[4]), f[5] - hi_part(f[5]));
        l.w = pack_hi2(f[6] - hi_part(f[6]), f[7] - hi_part(f[7]));
        size_t base = (size_t)kc * 32768;
        *(uint4*)(wsB + base + (size_t)(((sub * 2 + 0) * 8 + nt) * 64 + ln) * 16) = h;
        *(uint4*)(wsB + base + (size_t)(((sub * 2 + 1) * 8 + nt) * 64 + ln) * 16) = l;
    }
}

// ---------------------------------------------------------------------------
// main: 1024 blocks x 256 threads. Block = 16 rows x 128 cols x full K.
// 4 waves = (nh 0..1) x (ks 0..1): wave tile 16m x 64n over K-half 2048.
// R10 rationale (rocprof r9 post-mortem): R8's launch_bounds(512,4) capped
// VGPR at 128 < the ~180 live set -> compiler spilled prefetch buffers to
// scratch (VGPR=64, WRITE_SIZE=770MB, 504us = 2.5x regression). TLP must
// come with a register diet: halving the m-tile (mt loop removed) halves
// A-buffers and acc -> ~135 live regs, fits launch_bounds(256,3) cap (~170)
// with NO spill. Grid 1024 -> 3 blocks/CU (VGPR-limited) = 3 waves/SIMD,
// 1.5x r4's TLP at unchanged total issue work. Inner body otherwise
// byte-identical to the r4-verified 202us kernel (mt=0 slice).
// No LDS/barriers in K-loop; sched_barrier(0) pins batched load issue
// (r5 failure: compiler sank loads -> serial latency chain).
// ---------------------------------------------------------------------------
__global__ __launch_bounds__(256, 3)
void moe_mfma(const float* __restrict__ x,
              const float* __restrict__ noise,
              const char* __restrict__ wsB,
              float* __restrict__ gates,
              float* __restrict__ dst,      // partials (atomicTail=0) or load (=1)
              int atomicTail)
{
    __shared__ float Ls[RT * 132];   // 8448 B combined-logits tile
    __shared__ float red[256];

    const int tid  = threadIdx.x;
    const int w    = tid >> 6;       // 0..3
    const int lane = tid & 63;
    const int nh   = w & 1;          // n-half: cols nh*64 .. +63
    const int ks   = w >> 1;         // K-half: k in [ks*2048, ks*2048+2048)
    const int rb   = blockIdx.x * RT;

    const int m16 = lane & 15;
    const int q   = lane >> 4;

    const float* xr0 = x + (size_t)(rb + m16) * DD + ks * 2048 + q * 8;
    const uint4* bbase = (const uint4*)wsB + (size_t)ks * NCH * 2048 + nh * 4 * 64 + lane;

    f32x4 acc[4];
#pragma unroll
    for (int nt = 0; nt < 4; ++nt) acc[nt] = (f32x4){0.f, 0.f, 0.f, 0.f};

    auto load_A = [&](int ch, float4* a) {
#pragma unroll
        for (int sub = 0; sub < 2; ++sub) {
            const float* p = xr0 + ch * 64 + sub * 32;
            a[sub * 2 + 0] = *(const float4*)p;
            a[sub * 2 + 1] = *(const float4*)(p + 4);
        }
    };
    auto load_B = [&](int ch, int sub, uint4* b) {
        const uint4* p = bbase + (size_t)ch * 2048;
#pragma unroll
        for (int prec = 0; prec < 2; ++prec)
#pragma unroll
            for (int nt = 0; nt < 4; ++nt)
                b[prec * 4 + nt] = p[((sub * 2 + prec) * 8 + nt) * 64];
    };
    auto compute_sub = [&](const float4* a, int sub, const uint4* b) {
        uint4 h, l;
        split_pack(a[sub * 2 + 0], a[sub * 2 + 1], h, l);
        const s16x8 ah = __builtin_bit_cast(s16x8, h);
        const s16x8 al = __builtin_bit_cast(s16x8, l);
#pragma unroll
        for (int nt = 0; nt < 4; ++nt) {
            const s16x8 bh = __builtin_bit_cast(s16x8, b[nt]);
            const s16x8 bl = __builtin_bit_cast(s16x8, b[4 + nt]);
            acc[nt] = __builtin_amdgcn_mfma_f32_16x16x32_bf16(ah, bh, acc[nt], 0, 0, 0);
            acc[nt] = __builtin_amdgcn_mfma_f32_16x16x32_bf16(ah, bl, acc[nt], 0, 0, 0);
            acc[nt] = __builtin_amdgcn_mfma_f32_16x16x32_bf16(al, bh, acc[nt], 0, 0, 0);
        }
    };

    float4 A0[4], A1[4];
    uint4  B0[8], B1[8];
    load_A(0, A0);
    load_B(0, 0, B0);
    load_B(0, 1, B1);
    __builtin_amdgcn_sched_barrier(0);

    for (int ch = 0; ch < NCH; ch += 2) {
        // ---- chunk ch : consumes A0, B0(sub0), B1(sub1) ----
        load_A(ch + 1, A1);                       // HBM prefetch, 1 chunk ahead
        __builtin_amdgcn_sched_barrier(0);        // pin: issue before compute
        compute_sub(A0, 0, B0);
        load_B(ch + 1, 0, B0);                    // L2 refill, 1 chunk ahead
        __builtin_amdgcn_sched_barrier(0);
        compute_sub(A0, 1, B1);
        load_B(ch + 1, 1, B1);
        __builtin_amdgcn_sched_barrier(0);

        // ---- chunk ch+1 : consumes A1, refreshed B0/B1 ----
        const int nx = (ch + 2 < NCH) ? ch + 2 : NCH - 1;  // clamped redundant prefetch
        load_A(nx, A0);
        __builtin_amdgcn_sched_barrier(0);
        compute_sub(A1, 0, B0);
        load_B(nx, 0, B0);
        __builtin_amdgcn_sched_barrier(0);
        compute_sub(A1, 1, B1);
        load_B(nx, 1, B1);
        __builtin_amdgcn_sched_barrier(0);
    }

    // ---- combine K-halves in LDS (the only barriers in the kernel) ----
    const int q4 = lane >> 4, cc = lane & 15;
    if (ks == 0) {
#pragma unroll
        for (int nt = 0; nt < 4; ++nt)
#pragma unroll
            for (int r = 0; r < 4; ++r)
                Ls[(q4 * 4 + r) * 132 + nh * 64 + nt * 16 + cc] = acc[nt][r];
    }
    __syncthreads();
    if (ks == 1) {
#pragma unroll
        for (int nt = 0; nt < 4; ++nt)
#pragma unroll
            for (int r = 0; r < 4; ++r)
                Ls[(q4 * 4 + r) * 132 + nh * 64 + nt * 16 + cc] += acc[nt][r];
    }
    __syncthreads();

    // ---- fused epilogue (verified r1-5): wave-per-row, lane = expert ----
    // R10: 4 waves x 4 rows each.
    float loadAcc = 0.f;
    for (int rr = 0; rr < 4; ++rr) {
        const int row = w * 4 + rr;
        const float clean = Ls[row * 132 + lane];
        const float rawn  = Ls[row * 132 + 64 + lane];
        const float nz    = noise[(size_t)(rb + row) * EE + lane];

        const float sp = fmaxf(rawn, 0.f) + log1pf(expf(-fabsf(rawn)));
        const float sd = sp + 0.01f;
        const float noisy = clean + nz * sd;

        float m = noisy;
#pragma unroll
        for (int off = 32; off; off >>= 1) m = fmaxf(m, __shfl_xor(m, off));
        const float ex = expf(noisy - m);
        float s = ex;
#pragma unroll
        for (int off = 32; off; off >>= 1) s += __shfl_xor(s, off);
        const float p = ex / s;

        float cur = p;
        int selrank = -1;
        float v[9];
#pragma unroll
        for (int j = 0; j < 9; ++j) {
            float bv = cur;
            int   bi = lane;
#pragma unroll
            for (int off = 32; off; off >>= 1) {
                const float ov = __shfl_xor(bv, off);
                const int   oi = __shfl_xor(bi, off);
                if (ov > bv || (ov == bv && oi < bi)) { bv = ov; bi = oi; }
            }
            v[j] = bv;
            if (lane == bi) { cur = -1.f; if (j < TK) selrank = j; }
        }

        float denom = 0.f;
#pragma unroll
        for (int j = 0; j < TK; ++j) denom += expf(v[j] - v[0]);
        const float gate = (selrank >= 0) ? (expf(p - v[0]) / denom) : 0.f;
        gates[(size_t)(rb + row) * EE + lane] = gate;

        const float thr_in  = v[8];
        const float thr_out = v[7];
        const bool  is_in   = noisy > thr_in;
        const float a = (clean - (is_in ? thr_in : thr_out)) / sd;
        loadAcc += 0.5f * (1.f + erff(a * 0.70710678118654752f));
    }

    red[w * 64 + lane] = loadAcc;
    __syncthreads();
    if (tid < 64) {
        const float s = red[tid] + red[64 + tid] + red[128 + tid] + red[192 + tid];
        if (atomicTail) atomicAdd(&dst[tid], s);                 // fallback path
        else            dst[(size_t)blockIdx.x * 64 + tid] = s;  // coalesced
    }
}

// ---------------------------------------------------------------------------
// reduce: 1024x64 partials -> load[64]. One block; coalesced column reads.
// ---------------------------------------------------------------------------
__global__ __launch_bounds__(256, 1)
void reduce_load(const float* __restrict__ partial, float* __restrict__ load)
{
    __shared__ float red2[256];
    const int t   = threadIdx.x;
    const int e   = t & 63;
    const int seg = t >> 6;          // 4 segments x 256 blocks
    float s = 0.f;
#pragma unroll 4
    for (int b = seg * 256; b < seg * 256 + 256; ++b)
        s += partial[(size_t)b * 64 + e];
    red2[t] = s;
    __syncthreads();
    if (t < 64)
        load[t] = red2[t] + red2[64 + t] + red2[128 + t] + red2[192 + t];
}

extern "C" void kernel_launch(void* const* d_in, const int* in_sizes, int n_in,
                              void* d_out, int out_size, void* d_ws, size_t ws_size,
                              hipStream_t stream)
{
    const float* x     = (const float*)d_in[0];
    const float* wg    = (const float*)d_in[1];
    const float* wn    = (const float*)d_in[2];
    const float* noise = (const float*)d_in[3];
    float* gates = (float*)d_out;
    float* load  = (float*)d_out + (size_t)BB * EE;
    char*  wsB   = (char*)d_ws;                          // 2 MB B-stream

    const size_t wsB_bytes     = (size_t)(DD / 64) * 32768;          // 2 MB
    const size_t partial_bytes = (size_t)(BB / RT) * EE * sizeof(float); // 256 KB
    const bool   fits = ws_size >= wsB_bytes + partial_bytes;

    hipLaunchKernelGGL(prep_w, dim3(DD / 64), dim3(256), 0, stream, wg, wn, wsB);

    if (fits) {
        float* partial = (float*)(wsB + wsB_bytes);
        hipLaunchKernelGGL(moe_mfma, dim3(BB / RT), dim3(256), 0, stream,
                           x, noise, wsB, gates, partial, 0);
        hipLaunchKernelGGL(reduce_load, dim3(1), dim3(256), 0, stream, partial, load);
    } else {
        // harness-verified fallback: memset + device-scope atomic tail
        hipMemsetAsync(load, 0, EE * sizeof(float), stream);
        hipLaunchKernelGGL(moe_mfma, dim3(BB / RT), dim3(256), 0, stream,
                           x, noise, wsB, gates, load, 1);
    }
}

// Round 15
// 406.091 us; speedup vs baseline: 1.9014x; 1.2355x over previous
//
#include <hip/hip_runtime.h>
#include <math.h>

#define BB 16384
#define DD 4096
#define EE 64
#define TK 8
#define RT 32            // rows per block; grid = 512 (2 blocks/CU, all resident)
#define NCHUNK 32        // K chunks of 64 over full K=4096

typedef __attribute__((ext_vector_type(8))) short s16x8;
typedef __attribute__((ext_vector_type(4))) float f32x4;

__device__ inline unsigned pack_hi2(float a, float b) {
    return (__float_as_uint(a) >> 16) | (__float_as_uint(b) & 0xFFFF0000u);
}
__device__ inline float hi_part(float a) {
    return __uint_as_float(__float_as_uint(a) & 0xFFFF0000u);
}
__device__ inline void split_pack(const float4& v0, const float4& v1, uint4& h, uint4& l) {
    h.x = pack_hi2(v0.x, v0.y); h.y = pack_hi2(v0.z, v0.w);
    h.z = pack_hi2(v1.x, v1.y); h.w = pack_hi2(v1.z, v1.w);
    l.x = pack_hi2(v0.x - hi_part(v0.x), v0.y - hi_part(v0.y));
    l.y = pack_hi2(v0.z - hi_part(v0.z), v0.w - hi_part(v0.w));
    l.z = pack_hi2(v1.x - hi_part(v1.x), v1.y - hi_part(v1.y));
    l.w = pack_hi2(v1.z - hi_part(v1.z), v1.w - hi_part(v1.w));
}

// async 16B global->LDS copy: LDS dest = wave-uniform base + lane*16
__device__ inline void gload_lds16(const void* g, void* l) {
    __builtin_amdgcn_global_load_lds(
        (const __attribute__((address_space(1))) unsigned int*)g,
        (__attribute__((address_space(3))) unsigned int*)l, 16, 0, 0);
}

// ---------------------------------------------------------------------------
// prep: [wg | wn] fp32 -> bf16 hi/lo in MFMA B-fragment order (verified r2-5).
// ws layout: [kchunk(64)][sub(2)][prec(2)][ntile(8)][lane(64)][16B]
// ---------------------------------------------------------------------------
__global__ __launch_bounds__(256, 1)
void prep_w(const float* __restrict__ wg, const float* __restrict__ wn,
            char* __restrict__ wsB)
{
    __shared__ float Wtmp[64 * 132];
    const int t  = threadIdx.x;
    const int kc = blockIdx.x;

#pragma unroll
    for (int i = 0; i < 8; ++i) {
        int fid = t + i * 256;
        int m   = fid >> 10;
        int id  = fid & 1023;
        int kk  = id >> 4;
        int n4  = id & 15;
        const float* src = (m ? wn : wg) + (size_t)(kc * 64 + kk) * EE + n4 * 4;
        float4 v = *(const float4*)src;
        *(float4*)&Wtmp[kk * 132 + m * 64 + n4 * 4] = v;
    }
    __syncthreads();

#pragma unroll
    for (int i = 0; i < 4; ++i) {
        int id  = t + i * 256;
        int sub = id >> 9;
        int nt  = (id >> 6) & 7;
        int ln  = id & 63;
        int n   = nt * 16 + (ln & 15);
        int k0  = sub * 32 + (ln >> 4) * 8;
        float f[8];
#pragma unroll
        for (int j = 0; j < 8; ++j) f[j] = Wtmp[(k0 + j) * 132 + n];
        uint4 h, l;
        h.x = pack_hi2(f[0], f[1]); h.y = pack_hi2(f[2], f[3]);
        h.z = pack_hi2(f[4], f[5]); h.w = pack_hi2(f[6], f[7]);
        l.x = pack_hi2(f[0] - hi_part(f[0]), f[1] - hi_part(f[1]));
        l.y = pack_hi2(f[2] - hi_part(f[2]), f[3] - hi_part(f[3]));
        l.z = pack_hi2(f[4] - hi_part(f[4]), f[5] - hi_part(f[5]));
        l.w = pack_hi2(f[6] - hi_part(f[6]), f[7] - hi_part(f[7]));
        size_t base = (size_t)kc * 32768;
        *(uint4*)(wsB + base + (size_t)(((sub * 2 + 0) * 8 + nt) * 64 + ln) * 16) = h;
        *(uint4*)(wsB + base + (size_t)(((sub * 2 + 1) * 8 + nt) * 64 + ln) * 16) = l;
    }
}

// ---------------------------------------------------------------------------
// main R12: LDS-staged double-buffered pipeline (s5/m97 structure).
// Rationale (r4/r9/r11 counters): register-resident B double-buffer is
// unholdable -- compiler either spills (r9: VGPR cap 128 < live set,
// WRITE_SIZE 770MB) or sinks loads into a serial latency chain (r5, r11:
// VGPR=68 < the 64 regs B0+B1 need, 225us). LDS staging costs ZERO VGPRs
// for in-flight data: B (32KB/chunk, already in fragment order in wsB)
// goes global_load_lds -> LDS; A (8KB/chunk) is reg-staged (8 VGPRs in
// flight) + split_pack once at stage time, stored in fragment order so all
// K-loop ds_reads are lane-contiguous b128 (conflict-free).
// 4 waves x (2 n-tiles each) x full K: no cross-wave combine. One barrier
// per chunk; __syncthreads' implicit vmcnt(0) drain completes the async
// copies (m97 semantics). LDS 80KB dynamic = exactly 2 blocks/CU; grid 512
// = all blocks co-resident. Epilogue reuses the staging LDS (post-barrier).
// ---------------------------------------------------------------------------
__global__ __launch_bounds__(256, 2)
void moe_mfma(const float* __restrict__ x,
              const float* __restrict__ noise,
              const char* __restrict__ wsB,
              float* __restrict__ gates,
              float* __restrict__ dst,      // partials (atomicTail=0) or load (=1)
              int atomicTail)
{
    extern __shared__ char smem[];   // 81920 B: A bufs @0,8192 ; B bufs @16384,+32768

    const int tid  = threadIdx.x;
    const int w    = tid >> 6;       // 0..3, owns n-tiles {2w, 2w+1}
    const int lane = tid & 63;
    const int rb   = blockIdx.x * RT;

    // staging decomposition: thread -> (row, 8k-group)
    const int srow = tid >> 3;           // 0..31
    const int skg  = tid & 7;            // 0..7  (k = skg*8 .. +8 within chunk)
    const int smt  = srow >> 4, sm16 = srow & 15;
    const int ssub = skg >> 2,  sq   = skg & 3;
    const int slane = sm16 + sq * 16;    // fragment lane this thread feeds
    const float* gA0 = x + (size_t)(rb + srow) * DD + skg * 8;

    f32x4 acc[2][2];
#pragma unroll
    for (int mt = 0; mt < 2; ++mt)
#pragma unroll
        for (int ntl = 0; ntl < 2; ++ntl) acc[mt][ntl] = (f32x4){0.f, 0.f, 0.f, 0.f};

    auto stageA_write = [&](int buf, const float4& fa, const float4& fb) {
        uint4 h, l;
        split_pack(fa, fb, h, l);
        char* Ad = smem + buf * 8192;
        *(uint4*)(Ad + (size_t)(((ssub * 2 + 0) * 2 + smt) * 64 + slane) * 16) = h;
        *(uint4*)(Ad + (size_t)(((ssub * 2 + 1) * 2 + smt) * 64 + slane) * 16) = l;
    };
    auto stageB_issue = [&](int ch, int buf) {
        char* Bd = smem + 16384 + buf * 32768 + w * 8192;
        const char* gB = wsB + (size_t)ch * 32768 + w * 8192 + (size_t)lane * 16;
#pragma unroll
        for (int i = 0; i < 8; ++i)
            gload_lds16(gB + i * 1024, Bd + i * 1024);
    };
    auto compute = [&](int buf) {
        const char* Ab = smem + buf * 8192;
        const char* Bb = smem + 16384 + buf * 32768;
#pragma unroll
        for (int sub = 0; sub < 2; ++sub) {
            s16x8 ah[2], al[2];
#pragma unroll
            for (int mt = 0; mt < 2; ++mt) {
                ah[mt] = *(const s16x8*)(Ab + (size_t)(((sub * 2 + 0) * 2 + mt) * 64 + lane) * 16);
                al[mt] = *(const s16x8*)(Ab + (size_t)(((sub * 2 + 1) * 2 + mt) * 64 + lane) * 16);
            }
#pragma unroll
            for (int ntl = 0; ntl < 2; ++ntl) {
                const int ntg = w * 2 + ntl;
                const s16x8 bh = *(const s16x8*)(Bb + (size_t)(((sub * 2 + 0) * 8 + ntg) * 64 + lane) * 16);
                const s16x8 bl = *(const s16x8*)(Bb + (size_t)(((sub * 2 + 1) * 8 + ntg) * 64 + lane) * 16);
#pragma unroll
                for (int mt = 0; mt < 2; ++mt) {
                    acc[mt][ntl] = __builtin_amdgcn_mfma_f32_16x16x32_bf16(ah[mt], bh, acc[mt][ntl], 0, 0, 0);
                    acc[mt][ntl] = __builtin_amdgcn_mfma_f32_16x16x32_bf16(ah[mt], bl, acc[mt][ntl], 0, 0, 0);
                    acc[mt][ntl] = __builtin_amdgcn_mfma_f32_16x16x32_bf16(al[mt], bh, acc[mt][ntl], 0, 0, 0);
                }
            }
        }
    };

    // ---- prologue: stage chunk 0 into buf 0 ----
    {
        const float* p = gA0;
        float4 fa = *(const float4*)p, fb = *(const float4*)(p + 4);
        stageB_issue(0, 0);
        stageA_write(0, fa, fb);
    }
    __syncthreads();   // drains gload_lds (vmcnt) + ds_write (lgkm)

    // ---- K loop: one barrier per chunk ----
    for (int ch = 0; ch < NCHUNK; ++ch) {
        const int cur = ch & 1;
        const int nx  = (ch + 1 < NCHUNK) ? ch + 1 : NCHUNK - 1;  // clamped redundant
        const float* p = gA0 + nx * 64;
        float4 fa = *(const float4*)p, fb = *(const float4*)(p + 4); // HBM, fire early
        stageB_issue(nx, cur ^ 1);                                   // L2->LDS, fire
        __builtin_amdgcn_sched_barrier(0);     // pin issue before compute
        compute(cur);
        stageA_write(cur ^ 1, fa, fb);         // vmcnt wait auto-inserted for fa/fb
        __syncthreads();                       // drain + buffer swap
    }

    // ---- epilogue: reuse staging LDS (all staging drained by last barrier) ----
    float* Ls  = (float*)smem;             // [32][132] combined logits
    float* red = (float*)(smem + 16896);   // [256]

    const int q4 = lane >> 4, cc = lane & 15;
#pragma unroll
    for (int mt = 0; mt < 2; ++mt)
#pragma unroll
        for (int ntl = 0; ntl < 2; ++ntl)
#pragma unroll
            for (int r = 0; r < 4; ++r)
                Ls[(mt * 16 + q4 * 4 + r) * 132 + (w * 2 + ntl) * 16 + cc] = acc[mt][ntl][r];
    __syncthreads();

    // fused epilogue (verified r1-5): wave-per-row, lane = expert; 4 waves x 8 rows
    float loadAcc = 0.f;
    for (int rr = 0; rr < 8; ++rr) {
        const int row = w * 8 + rr;
        const float clean = Ls[row * 132 + lane];
        const float rawn  = Ls[row * 132 + 64 + lane];
        const float nz    = noise[(size_t)(rb + row) * EE + lane];

        const float sp = fmaxf(rawn, 0.f) + log1pf(expf(-fabsf(rawn)));
        const float sd = sp + 0.01f;
        const float noisy = clean + nz * sd;

        float m = noisy;
#pragma unroll
        for (int off = 32; off; off >>= 1) m = fmaxf(m, __shfl_xor(m, off));
        const float ex = expf(noisy - m);
        float s = ex;
#pragma unroll
        for (int off = 32; off; off >>= 1) s += __shfl_xor(s, off);
        const float p = ex / s;

        float cur = p;
        int selrank = -1;
        float v[9];
#pragma unroll
        for (int j = 0; j < 9; ++j) {
            float bv = cur;
            int   bi = lane;
#pragma unroll
            for (int off = 32; off; off >>= 1) {
                const float ov = __shfl_xor(bv, off);
                const int   oi = __shfl_xor(bi, off);
                if (ov > bv || (ov == bv && oi < bi)) { bv = ov; bi = oi; }
            }
            v[j] = bv;
            if (lane == bi) { cur = -1.f; if (j < TK) selrank = j; }
        }

        float denom = 0.f;
#pragma unroll
        for (int j = 0; j < TK; ++j) denom += expf(v[j] - v[0]);
        const float gate = (selrank >= 0) ? (expf(p - v[0]) / denom) : 0.f;
        gates[(size_t)(rb + row) * EE + lane] = gate;

        const float thr_in  = v[8];
        const float thr_out = v[7];
        const bool  is_in   = noisy > thr_in;
        const float a = (clean - (is_in ? thr_in : thr_out)) / sd;
        loadAcc += 0.5f * (1.f + erff(a * 0.70710678118654752f));
    }

    red[w * 64 + lane] = loadAcc;
    __syncthreads();
    if (tid < 64) {
        const float s = red[tid] + red[64 + tid] + red[128 + tid] + red[192 + tid];
        if (atomicTail) atomicAdd(&dst[tid], s);                 // fallback path
        else            dst[(size_t)blockIdx.x * 64 + tid] = s;  // coalesced
    }
}

// ---------------------------------------------------------------------------
// reduce: 512x64 partials -> load[64]. One block; coalesced column reads.
// ---------------------------------------------------------------------------
__global__ __launch_bounds__(256, 1)
void reduce_load(const float* __restrict__ partial, float* __restrict__ load)
{
    __shared__ float red2[256];
    const int t   = threadIdx.x;
    const int e   = t & 63;
    const int seg = t >> 6;          // 4 segments x 128 blocks
    float s = 0.f;
#pragma unroll 4
    for (int b = seg * 128; b < seg * 128 + 128; ++b)
        s += partial[(size_t)b * 64 + e];
    red2[t] = s;
    __syncthreads();
    if (t < 64)
        load[t] = red2[t] + red2[64 + t] + red2[128 + t] + red2[192 + t];
}

extern "C" void kernel_launch(void* const* d_in, const int* in_sizes, int n_in,
                              void* d_out, int out_size, void* d_ws, size_t ws_size,
                              hipStream_t stream)
{
    const float* x     = (const float*)d_in[0];
    const float* wg    = (const float*)d_in[1];
    const float* wn    = (const float*)d_in[2];
    const float* noise = (const float*)d_in[3];
    float* gates = (float*)d_out;
    float* load  = (float*)d_out + (size_t)BB * EE;
    char*  wsB   = (char*)d_ws;                          // 2 MB B-stream

    const size_t wsB_bytes     = (size_t)(DD / 64) * 32768;              // 2 MB
    const size_t partial_bytes = (size_t)(BB / RT) * EE * sizeof(float); // 128 KB
    const bool   fits = ws_size >= wsB_bytes + partial_bytes;
    const size_t ldsBytes = 81920;   // A 8K x2 + B 32K x2

    hipLaunchKernelGGL(prep_w, dim3(DD / 64), dim3(256), 0, stream, wg, wn, wsB);

    if (fits) {
        float* partial = (float*)(wsB + wsB_bytes);
        hipLaunchKernelGGL(moe_mfma, dim3(BB / RT), dim3(256), ldsBytes, stream,
                           x, noise, wsB, gates, partial, 0);
        hipLaunchKernelGGL(reduce_load, dim3(1), dim3(256), 0, stream, partial, load);
    } else {
        // harness-verified fallback: memset + device-scope atomic tail
        hipMemsetAsync(load, 0, EE * sizeof(float), stream);
        hipLaunchKernelGGL(moe_mfma, dim3(BB / RT), dim3(256), ldsBytes, stream,
                           x, noise, wsB, gates, load, 1);
    }
}